// Round 10
// baseline (613.378 us; speedup 1.0000x reference)
//
#include <hip/hip_runtime.h>
#include <math.h>

// R10 = R9 with the fused-basew coalescing fixed: wave-per-64-j, lanes split
// the i dimension (contiguous 256B loads), 6-shfl reduce per j. No W1T
// intermediate (would race inside one kernel). Everything else = R9.

#define T_ 64
#define M_ 256
#define K_ 6
#define B_ 256
#define H_ 256
#define L_ 128
#define V_ 780
#define E_ (T_*M_)       // 16384
#define ZD 383           // H+L-1
#define UD 638           // 2H+L-2
#define KP 384           // ZD padded for MFMA
#define VP 832           // V padded to 13*64
#define TAG_PAD 0x7fffffffu

typedef __attribute__((ext_vector_type(8))) _Float16 half8v;
typedef __attribute__((ext_vector_type(2))) _Float16 half2v;
typedef __attribute__((ext_vector_type(4))) float f32x4v;
typedef unsigned long long u64;

// ---------------- helpers ----------------

__device__ __forceinline__ float blk_sum(float v, float* red) {
    int j = threadIdx.x;
    #pragma unroll
    for (int o = 32; o > 0; o >>= 1) v += __shfl_down(v, o, 64);
    __syncthreads();
    if ((j & 63) == 0) red[j >> 6] = v;
    __syncthreads();
    return red[0] + red[1] + red[2] + red[3];
}

__device__ __forceinline__ float wave_sum(float v) {
    #pragma unroll
    for (int o = 32; o > 0; o >>= 1) v += __shfl_xor(v, o, 64);
    return v;
}

__device__ __forceinline__ _Float16 f2h(float x) { return (_Float16)x; }

// LLC-coherent (agent-scope) accessors for cross-block state
__device__ __forceinline__ u64 llc_load8(const u64* p) {
    return __hip_atomic_load(p, __ATOMIC_RELAXED, __HIP_MEMORY_SCOPE_AGENT);
}
__device__ __forceinline__ void llc_store8(u64* p, u64 v) {
    __hip_atomic_store(p, v, __ATOMIC_RELAXED, __HIP_MEMORY_SCOPE_AGENT);
}
__device__ __forceinline__ float llc_loadf(const float* p) {
    return __hip_atomic_load(p, __ATOMIC_RELAXED, __HIP_MEMORY_SCOPE_AGENT);
}

// ---------------- fused prep: basew (coalesced) + inits + W packs + wcls conv ----------------

#define S_BW (V_ * H_)                   // 199680 = 780 blocks exactly (MUST be first)
#define S_R0 256                         // hbuf PAD row
#define S_RT ((E_ + 1) * 128)            // hbuf2
#define S_H3 E_                          // hbuf3
#define S_CT 256                         // completion counter (word 0)
#define S_W0 65536                       // W0P  (16*8*64*8)
#define S_W1 65536                       // W1HP (16*8*64*8)
#define S_WH (VP * KP)                   // Wh
#define S_TOTAL (S_BW + S_R0 + S_RT + S_H3 + S_CT + S_W0 + S_W1 + S_WH)

__global__ __launch_bounds__(256) void prep_k(const float* __restrict__ W0,
        const float* __restrict__ W1, const float* __restrict__ wcls,
        const float* __restrict__ emb, const float* __restrict__ b1,
        float* __restrict__ hbuf, u64* __restrict__ hbuf2, u64* __restrict__ hbuf3,
        int* __restrict__ counter,
        _Float16* __restrict__ W0P, _Float16* __restrict__ W1HP,
        _Float16* __restrict__ Wh, float* __restrict__ basew) {
    __shared__ float cxs[256];
    int idx = blockIdx.x * 256 + threadIdx.x;
    if (idx < S_BW) {
        // block = one v (S_BW % 256 == 0). Coalesced basew:
        // wave w owns j = w*64..w*64+63; lanes split i (contiguous 256B loads).
        int v = blockIdx.x;
        int w = threadIdx.x >> 6, l = threadIdx.x & 63;
        cxs[threadIdx.x] = emb[(size_t)v * H_ + threadIdx.x];
        __syncthreads();
        for (int jj = 0; jj < 64; jj++) {
            int j = w * 64 + jj;
            const float* w1r = W1 + (size_t)j * (2 * H_ - 1);
            float p = 0.f;
            #pragma unroll
            for (int s = 0; s < 4; s++) {
                int i = s * 64 + l;
                if (i >= 1) p = fmaf(cxs[i], w1r[i], p);   // i in [1,255]
            }
            p = wave_sum(p);
            if (l == 0) basew[(size_t)v * H_ + j] = p + b1[j];
        }
        return;
    }
    idx -= S_BW;
    if (idx < S_R0) {
        hbuf[(size_t)E_ * H_ + idx] = (idx == 0) ? 1.f : 0.f;
        return;
    }
    idx -= S_R0;
    if (idx < S_RT) {
        int row = idx >> 7, cp = idx & 127;
        u64 val = 0ull;
        if (row == E_) {
            unsigned int lo = (cp == 0) ? 0x3C00u : 0u;   // fp16 1.0 in col 0
            val = ((u64)TAG_PAD << 32) | lo;
        }
        hbuf2[idx] = val;
        return;
    }
    idx -= S_RT;
    if (idx < S_H3) {
        hbuf3[idx] = 0ull;
        return;
    }
    idx -= S_H3;
    if (idx < S_CT) {
        if (idx == 0) counter[0] = 0;
        return;
    }
    idx -= S_CT;
    if (idx < S_W0) {
        // W0P[((nt*8+ks)*64+l)*8+e] = W0[(nt*16+(l&15)) * H + ks*32+(l>>4)*8+e]
        int e = idx & 7, l = (idx >> 3) & 63, ks = (idx >> 9) & 7, nt = idx >> 12;
        int jj = nt * 16 + (l & 15);
        int ii = ks * 32 + (l >> 4) * 8 + e;
        W0P[idx] = f2h(W0[(size_t)jj * H_ + ii]);
        return;
    }
    idx -= S_W0;
    if (idx < S_W1) {
        // same packing, but column map ii -> {0, 256..510} of W1
        int e = idx & 7, l = (idx >> 3) & 63, ks = (idx >> 9) & 7, nt = idx >> 12;
        int jj = nt * 16 + (l & 15);
        int ii = ks * 32 + (l >> 4) * 8 + e;
        float v = (ii == 0) ? W1[(size_t)jj * (2 * H_ - 1)]
                            : W1[(size_t)jj * (2 * H_ - 1) + 255 + ii];
        W1HP[idx] = f2h(v);
        return;
    }
    idx -= S_W1;
    if (idx < S_WH) {
        int v = idx / KP, k = idx - v * KP;
        float val = (v < V_ && k < ZD) ? wcls[(size_t)v * ZD + k] : 0.f;
        Wh[idx] = f2h(val);
    }
}

// ---------------- dataflow scan + FUSED msg GEMM/CE tail (R6 structure) ----------------

__global__ __launch_bounds__(256, 1) void scan_flow(float* __restrict__ hbuf,
        u64* __restrict__ hbuf2, u64* __restrict__ hbuf3,
        const _Float16* __restrict__ W0P, const float* __restrict__ b0, const float* __restrict__ s0p,
        const _Float16* __restrict__ W1HP, const float* __restrict__ s1p,
        const float* __restrict__ emb, const int* __restrict__ wid,
        const int* __restrict__ nhi, const float* __restrict__ nhw,
        const float* __restrict__ basew,
        const _Float16* __restrict__ Wh, const float* __restrict__ wbias,
        const int* __restrict__ pt, const int* __restrict__ dir,
        const int* __restrict__ bidx, const float* __restrict__ xtv,
        float* __restrict__ part) {
    int tid = threadIdx.x;
    int w = tid >> 6, l = tid & 63;
    int quad = l >> 4, col = l & 15;
    int m = blockIdx.x;
    int j0 = 4 * l;
    int cp = tid & 127;            // this thread's colpair (cols 2cp, 2cp+1)
    int rsel = tid >> 7;           // 0 or 1: rows {rsel, rsel+2, rsel+4}

    __shared__ __align__(16) _Float16 hn16[16][264];   // rows 0..5 staged
    __shared__ __align__(16) _Float16 zzs[4][264];     // per-wave zh strips
    __shared__ __align__(16) float Ys[6][256];
    __shared__ __align__(16) float y2s[256];
    // gemm-tail buffers
    __shared__ __align__(16) _Float16 As[64][392];
    __shared__ __align__(16) _Float16 Bsf[64][392];
    __shared__ __align__(16) float SCs[64][68];
    __shared__ float rmax[64], rsum[64], rval[64];
    __shared__ int   rargi[64];

    // ---- one-time: wave w's weight slices (nt = 4w..4w+3) into registers ----
    half8v w0f[4][8], w1f[4][8];
    #pragma unroll
    for (int q = 0; q < 4; q++) {
        int nt = 4 * w + q;
        #pragma unroll
        for (int ks = 0; ks < 8; ks++) {
            w0f[q][ks] = *(const half8v*)(W0P + ((size_t)(nt * 8 + ks) * 64 + l) * 8);
            w1f[q][ks] = *(const half8v*)(W1HP + ((size_t)(nt * 8 + ks) * 64 + l) * 8);
        }
    }

    float es0 = expf(s0p[0]);
    float es1 = expf(s1p[0]);
    float4 bj4 = *(const float4*)(b0 + j0);

    // ---- prologue: issue step-0 pair loads (3 per thread) ----
    unsigned int tagx[3];
    const u64* pp[3];
    u64 pvv[3];
    #pragma unroll
    for (int p = 0; p < 3; p++) {
        int row = 2 * p + rsel;
        int id = nhi[(size_t)m * K_ + row];              // e = 0*M_+m
        tagx[p] = (id < E_) ? (unsigned int)(id >> 8) + 1u : TAG_PAD;
        pp[p] = hbuf2 + ((size_t)id << 7) + cp;
        pvv[p] = llc_load8(pp[p]);
    }

    for (int t = 0; t < T_; t++) {
        int e = t * M_ + m;
        const float* wp = nhw + e * K_;

        // per-step scalars (cached loads; latency hides under validate/W0)
        float wk[K_];
        #pragma unroll
        for (int k = 0; k < K_; k++) wk[k] = wp[k];
        int wde = wid[e];
        float4 bw4 = *(const float4*)(basew + (size_t)wde * H_ + j0);
        float cx0 = emb[(size_t)wde * H_];

        // ---- batch-poll validate: one parallel RT per retry round ----
        for (;;) {
            bool ok = ((unsigned int)(pvv[0] >> 32) == tagx[0])
                   && ((unsigned int)(pvv[1] >> 32) == tagx[1])
                   && ((unsigned int)(pvv[2] >> 32) == tagx[2]);
            if (ok) break;
            __builtin_amdgcn_s_sleep(1);
            #pragma unroll
            for (int p = 0; p < 3; p++)
                if ((unsigned int)(pvv[p] >> 32) != tagx[p]) pvv[p] = llc_load8(pp[p]);
        }
        #pragma unroll
        for (int p = 0; p < 3; p++)
            *(unsigned int*)&hn16[2 * p + rsel][cp * 2] = (unsigned int)pvv[p];
        __syncthreads();                                           // S1: rows staged

        // ---- prefetch step t+1's pairs (fly under W0/phaseA/W1/final) ----
        if (t + 1 < T_) {
            #pragma unroll
            for (int p = 0; p < 3; p++) {
                int row = 2 * p + rsel;
                int id = nhi[(size_t)(e + M_) * K_ + row];
                tagx[p] = (id < E_) ? (unsigned int)(id >> 8) + 1u : TAG_PAD;
                pp[p] = hbuf2 + ((size_t)id << 7) + cp;
                pvv[p] = llc_load8(pp[p]);
            }
        }

        // ---- W0 GEMM via MFMA: A from LDS, B from registers ----
        f32x4v acc[4];
        #pragma unroll
        for (int q = 0; q < 4; q++) acc[q] = (f32x4v){0.f, 0.f, 0.f, 0.f};
        #pragma unroll
        for (int ks = 0; ks < 8; ks++) {
            half8v afr = *(const half8v*)&hn16[col][ks * 32 + quad * 8];
            #pragma unroll
            for (int q = 0; q < 4; q++)
                acc[q] = __builtin_amdgcn_mfma_f32_16x16x32_f16(afr, w0f[q][ks], acc[q], 0, 0, 0);
        }
        #pragma unroll
        for (int q = 0; q < 4; q++) {
            int nt = 4 * w + q;
            #pragma unroll
            for (int rr = 0; rr < 4; rr++) {
                int row = quad * 4 + rr;
                if (row < 6) Ys[row][nt * 16 + col] = acc[q][rr];
            }
        }
        __syncthreads();                                           // S2: Ys ready

        // ---- nonlinear phase A (wave-redundant): interleaved butterflies ----
        float y[K_][4];
        #pragma unroll
        for (int k = 0; k < K_; k++) {
            float4 yv = *(const float4*)&Ys[k][j0];
            y[k][0] = yv.x + bj4.x; y[k][1] = yv.y + bj4.y;
            y[k][2] = yv.z + bj4.z; y[k][3] = yv.w + bj4.w;
        }
        float c[K_];
        #pragma unroll
        for (int k = 0; k < K_; k++) {
            float cc = y[k][0] * y[k][0] + y[k][1] * y[k][1]
                     + y[k][2] * y[k][2] + y[k][3] * y[k][3];
            if (l == 0) cc -= y[k][0] * y[k][0];         // exclude j==0 term
            c[k] = cc;
        }
        #pragma unroll
        for (int o = 32; o > 0; o >>= 1) {
            #pragma unroll
            for (int k = 0; k < K_; k++) c[k] += __shfl_xor(c[k], o, 64);
        }
        float y0b[K_];
        #pragma unroll
        for (int k = 0; k < K_; k++) y0b[k] = __shfl(y[k][0], 0, 64);

        float ave[4] = {0.f, 0.f, 0.f, 0.f};
        float wsum = 0.f;
        #pragma unroll
        for (int k = 0; k < K_; k++) {
            float tm = es0 / (1.f + expf(-y0b[k])) + 1.1f;
            float scv = sqrtf((tm * tm - 1.f) / fmaxf(c[k], 1e-8f));
            #pragma unroll
            for (int c2 = 0; c2 < 4; c2++) {
                float h1v = (l == 0 && c2 == 0) ? tm : y[k][c2] * scv;
                ave[c2] += wk[k] * h1v;
            }
            wsum += wk[k];
        }
        float inv = 1.f / fmaxf(wsum, 1e-8f);
        float innl = 0.f;
        #pragma unroll
        for (int c2 = 0; c2 < 4; c2++) { ave[c2] *= inv; innl += ave[c2] * ave[c2]; }
        if (l == 0) innl -= 2.f * ave[0] * ave[0];       // j==0 contributes -ave0^2
        float inner = wave_sum(innl);
        float rsc = 1.f / sqrtf(fmaxf(-inner, 1e-8f));

        // each wave writes ITS OWN zz strip (no cross-wave barrier needed)
        #pragma unroll
        for (int c2 = 0; c2 < 4; c2++) {
            int j = j0 + c2;
            float h1m = ave[c2] * rsc;
            if (j == 0) {
                zzs[w][0] = f2h(sqrtf(fmaxf(cx0 * cx0 + h1m * h1m - 1.f, 1e-8f)));
            } else {
                zzs[w][j] = f2h(h1m);
            }
        }

        // ---- W1H GEMV via MFMA (K=256): A from own zz strip, B from registers ----
        f32x4v a2[4];
        #pragma unroll
        for (int q = 0; q < 4; q++) a2[q] = (f32x4v){0.f, 0.f, 0.f, 0.f};
        #pragma unroll
        for (int ks = 0; ks < 8; ks++) {
            half8v zfr = *(const half8v*)&zzs[w][ks * 32 + quad * 8];
            #pragma unroll
            for (int q = 0; q < 4; q++)
                a2[q] = __builtin_amdgcn_mfma_f32_16x16x32_f16(zfr, w1f[q][ks], a2[q], 0, 0, 0);
        }
        if (quad == 0) {
            #pragma unroll
            for (int q = 0; q < 4; q++) y2s[(4 * w + q) * 16 + col] = a2[q][0];
        }
        __syncthreads();                                           // S4: y2 ready

        // ---- final nonlinear + publish row (wave 0; tagged pairs first) ----
        if (w == 0) {
            float4 y2v = *(const float4*)&y2s[j0];
            float y2[4] = {y2v.x + bw4.x, y2v.y + bw4.y, y2v.z + bw4.z, y2v.w + bw4.w};
            float c2s = y2[0] * y2[0] + y2[1] * y2[1] + y2[2] * y2[2] + y2[3] * y2[3];
            if (l == 0) c2s -= y2[0] * y2[0];
            float ssq2 = wave_sum(c2s);
            float y20 = __shfl(y2[0], 0, 64);
            float tm2 = es1 / (1.f + expf(-y20)) + 1.1f;
            float sc2 = sqrtf((tm2 * tm2 - 1.f) / fmaxf(ssq2, 1e-8f));
            float hv0 = (l == 0) ? tm2 : y2[0] * sc2;
            float hv1 = y2[1] * sc2, hv2 = y2[2] * sc2, hv3 = y2[3] * sc2;

            // tagged fp16 pairs FIRST (what scan consumers wait on)
            unsigned int tag = (unsigned int)t + 1u;
            union { half2v h; unsigned int u; } c01, c23;
            c01.h.x = f2h(hv0); c01.h.y = f2h(hv1);
            c23.h.x = f2h(hv2); c23.h.y = f2h(hv3);
            u64* pb = hbuf2 + ((size_t)e << 7) + 2 * l;
            llc_store8(pb,     ((u64)tag << 32) | c01.u);
            llc_store8(pb + 1, ((u64)tag << 32) | c23.u);

            // tagged exact f32 h0 for the fused gemm tail (lane 0)
            if (l == 0) {
                union { float f; unsigned int u; } h0b; h0b.f = tm2;
                llc_store8(hbuf3 + e, ((u64)tag << 32) | h0b.u);
            }

            // plain f32 row for stoproot (kernel-boundary visible, cached reads)
            float4 out4 = {hv0, hv1, hv2, hv3};
            *(float4*)(hbuf + (size_t)e * H_ + j0) = out4;
        }
        // no trailing barrier: S1(t+1) orders next-step hn16 writes after S4(t)
    }

    // ================= fused msg GEMM + CE tail =================
    {
        int m0 = m * 64;   // this block's 64 e-rows

        // ---- stage As cols 0..255 from hbuf2 tagged pairs (32/thread, batch-poll) ----
        u64 gpv[32];
        #pragma unroll
        for (int i = 0; i < 32; i++) {
            int p = tid + i * 256;
            int row = p >> 7, cpp = p & 127;
            gpv[i] = llc_load8(hbuf2 + ((size_t)(m0 + row) << 7) + cpp);
        }
        for (;;) {
            bool ok = true;
            #pragma unroll
            for (int i = 0; i < 32; i++) {
                int row = (tid + i * 256) >> 7;
                unsigned int tg = (unsigned int)((m0 + row) >> 8) + 1u;
                if ((unsigned int)(gpv[i] >> 32) != tg) ok = false;
            }
            if (ok) break;
            __builtin_amdgcn_s_sleep(1);
            #pragma unroll
            for (int i = 0; i < 32; i++) {
                int p = tid + i * 256;
                int row = p >> 7, cpp = p & 127;
                unsigned int tg = (unsigned int)((m0 + row) >> 8) + 1u;
                if ((unsigned int)(gpv[i] >> 32) != tg)
                    gpv[i] = llc_load8(hbuf2 + ((size_t)(m0 + row) << 7) + cpp);
            }
        }
        #pragma unroll
        for (int i = 0; i < 32; i++) {
            int p = tid + i * 256;
            int row = p >> 7, cpp = p & 127;
            *(unsigned int*)&As[row][2 * cpp] = (unsigned int)gpv[i];
        }
        // ---- ctx cols 256..383 from xtv ----
        #pragma unroll
        for (int i = 0; i < 16; i++) {
            int p = tid + i * 256;
            int row = p >> 6, k2 = (p & 63) * 2;
            int bi = bidx[m0 + row];
            int ca = 256 + k2;
            half2v hv;
            hv.x = (ca <= 382) ? f2h(xtv[(size_t)bi * L_ + (ca - 255)]) : (_Float16)0.f;
            hv.y = (ca + 1 <= 382) ? f2h(xtv[(size_t)bi * L_ + (ca - 254)]) : (_Float16)0.f;
            *(half2v*)&As[row][ca] = hv;
        }
        // ---- col 0: -z0 from exact f32 h0 (hbuf3, self-validating) ----
        if (tid < 64) {
            int e2 = m0 + tid;
            unsigned int tg = (unsigned int)(e2 >> 8) + 1u;
            u64 hv3 = llc_load8(hbuf3 + e2);
            while ((unsigned int)(hv3 >> 32) != tg) {
                __builtin_amdgcn_s_sleep(1);
                hv3 = llc_load8(hbuf3 + e2);
            }
            union { unsigned int u; float f; } h0c; h0c.u = (unsigned int)hv3;
            int bi = bidx[e2];
            float c0 = xtv[(size_t)bi * L_];
            float z0 = sqrtf(fmaxf(h0c.f * h0c.f + c0 * c0 - 1.f, 1e-8f));
            As[tid][0] = f2h(-z0);
            rmax[tid] = -1e30f; rsum[tid] = 0.f; rargi[tid] = 0; rval[tid] = 0.f;
        }
        __syncthreads();

        int q8 = quad * 8;
        for (int nt = 0; nt < 13; nt++) {
            int n0 = nt * 64;
            #pragma unroll
            for (int i = 0; i < 12; i++) {
                int uu = tid + i * 256;
                int row = uu / 48, c8 = (uu % 48) * 8;
                *(uint4*)&Bsf[row][c8] = *(const uint4*)(Wh + (size_t)(n0 + row) * KP + c8);
            }
            __syncthreads();

            f32x4v gacc[4];
            #pragma unroll
            for (int mt = 0; mt < 4; mt++) gacc[mt] = (f32x4v){0.f, 0.f, 0.f, 0.f};
            #pragma unroll
            for (int ks = 0; ks < 12; ks++) {
                half8v bfr = *(const half8v*)&Bsf[w * 16 + col][ks * 32 + q8];
                #pragma unroll
                for (int mt = 0; mt < 4; mt++) {
                    half8v afr = *(const half8v*)&As[mt * 16 + col][ks * 32 + q8];
                    gacc[mt] = __builtin_amdgcn_mfma_f32_16x16x32_f16(afr, bfr, gacc[mt], 0, 0, 0);
                }
            }
            int ncol = n0 + w * 16 + col;
            float bias = (ncol < V_) ? wbias[ncol] : 0.f;
            #pragma unroll
            for (int mt = 0; mt < 4; mt++) {
                #pragma unroll
                for (int rr = 0; rr < 4; rr++)
                    SCs[mt * 16 + quad * 4 + rr][w * 16 + col] = 2.f + 2.f * gacc[mt][rr] + bias;
            }
            __syncthreads();

            {
                int row = tid >> 2, prt = tid & 3;
                int tg = pt[m0 + row];
                float vals[16];
                float lm = -1e30f; int li = 0;
                #pragma unroll
                for (int cc = 0; cc < 16; cc++) {
                    int nc = n0 + prt * 16 + cc;
                    float x = (nc < V_) ? SCs[row][prt * 16 + cc] : -1e30f;
                    vals[cc] = x;
                    if (x > lm) { lm = x; li = nc; }
                    if (nc == tg) rval[row] = x;
                }
                #pragma unroll
                for (int o = 1; o < 4; o <<= 1) {
                    float om = __shfl_xor(lm, o, 64);
                    int   oi = __shfl_xor(li, o, 64);
                    if (om > lm || (om == lm && oi < li)) { lm = om; li = oi; }
                }
                float ls = 0.f;
                #pragma unroll
                for (int cc = 0; cc < 16; cc++) {
                    int nc = n0 + prt * 16 + cc;
                    if (nc < V_) ls += expf(vals[cc] - lm);
                }
                #pragma unroll
                for (int o = 1; o < 4; o <<= 1) ls += __shfl_xor(ls, o, 64);
                if (prt == 0) {
                    float om = rmax[row], os = rsum[row];
                    float nm = fmaxf(om, lm);
                    rsum[row] = os * expf(om - nm) + ls * expf(lm - nm);
                    if (lm > om) rargi[row] = li;
                    rmax[row] = nm;
                }
            }
            __syncthreads();
        }

        if (tid < 64) {
            int e2 = m0 + tid;
            int tg = pt[e2];
            float pm = (float)dir[e2];
            float lse = rmax[tid] + logf(rsum[tid]);
            float lloss = pm * (lse - rval[tid]);
            float lhit  = pm * ((rargi[tid] == tg) ? 1.f : 0.f);
            float lpm   = pm;
            lloss = wave_sum(lloss);
            lhit  = wave_sum(lhit);
            lpm   = wave_sum(lpm);
            if (tid == 0) {
                float* pr = part + (size_t)m * 8;
                pr[0] = lloss; pr[1] = lhit; pr[2] = lpm;
                pr[3] = 0.f; pr[4] = 0.f;
            }
        }
    }
}

// ---------------- fused stop head (blocks 0..255) + root (256..511) + last-block finalize ----------------

__global__ __launch_bounds__(256) void stoproot_k(const float* __restrict__ hbuf,
        const float* __restrict__ emb, const float* __restrict__ xtv,
        const int* __restrict__ wid, const int* __restrict__ noi, const float* __restrict__ now_w,
        const int* __restrict__ bidx, const int* __restrict__ dir,
        const int* __restrict__ rwid, const int* __restrict__ roi, const float* __restrict__ row_w,
        const float* __restrict__ wcls, const float* __restrict__ wbias,
        const float* __restrict__ ucls, const float* __restrict__ ubias,
        float* __restrict__ part, int* __restrict__ counter,
        float* __restrict__ out) {
    __shared__ float red[256];
    __shared__ int   redi[256];
    __shared__ float shs[4];
    __shared__ float ctxs[L_];
    __shared__ float sc[V_];
    __shared__ float red2[4][2];
    __shared__ float fred[256][5];
    __shared__ int   lastf;

    if (blockIdx.x < 256) {
        int w = threadIdx.x >> 6, l = threadIdx.x & 63;
        int wg = blockIdx.x * 4 + w;

        float ua0[4], ub0[4], ua1[4], ub1[4], uc0[2], uc1[2];
        #pragma unroll
        for (int s = 0; s < 4; s++) {
            int j = s * 64 + l;
            ua0[s] = ucls[j];        ub0[s] = ucls[255 + j];
            ua1[s] = ucls[UD + j];   ub1[s] = ucls[UD + 255 + j];
        }
        #pragma unroll
        for (int s = 0; s < 2; s++) {
            int j = s * 64 + l;
            uc0[s] = ucls[510 + j];  uc1[s] = ucls[UD + 510 + j];
        }
        float u00 = ucls[0], u10 = ucls[UD];
        float ubs0 = ubias[0], ubs1 = ubias[1];

        float lloss = 0.f, lhit = 0.f;
        for (int i = 0; i < 16; i++) {
            int e = wg * 16 + i;
            const int*   ip = noi + e * K_;
            const float* wp = now_w + e * K_;
            float ave[4] = {0.f, 0.f, 0.f, 0.f};
            float wsum = 0.f;
            #pragma unroll
            for (int k = 0; k < K_; k++) {
                int id = ip[k]; float wt = wp[k];
                wsum += wt;
                const float* hr = hbuf + (size_t)id * H_;
                #pragma unroll
                for (int s = 0; s < 4; s++) ave[s] += wt * hr[s * 64 + l];
            }
            float inv = 1.f / fmaxf(wsum, 1e-8f);
            float innl = 0.f;
            #pragma unroll
            for (int s = 0; s < 4; s++) { ave[s] *= inv; innl += ave[s] * ave[s]; }
            if (l == 0) innl -= 2.f * ave[0] * ave[0];
            float inner = wave_sum(innl);
            float cs = 1.f / sqrtf(fmaxf(-inner, 1e-8f));

            int we = wid[e], bi = bidx[e];
            const float* er = emb + (size_t)we * H_;
            const float* cr = xtv + (size_t)bi * L_;

            float p0 = 0.f, p1 = 0.f;
            #pragma unroll
            for (int s = 0; s < 4; s++) {
                float cx = er[s * 64 + l];
                float co = ave[s] * cs;
                if (s == 0 && l == 0) {
                    float ctx0 = cr[0];
                    float t1sq = fmaxf(cx * cx + co * co - 1.f, 1e-8f);
                    float sh0 = sqrtf(fmaxf(t1sq + ctx0 * ctx0 - 1.f, 1e-8f));
                    p0 += -sh0 * u00; p1 += -sh0 * u10;
                } else {
                    p0 += cx * ua0[s] + co * ub0[s];
                    p1 += cx * ua1[s] + co * ub1[s];
                }
                if (s < 2) {
                    int j = s * 64 + l;
                    if (j >= 1) {
                        float ctx = cr[j];
                        p0 += ctx * uc0[s]; p1 += ctx * uc1[s];
                    }
                }
            }
            p0 = wave_sum(p0); p1 = wave_sum(p1);
            if (l == 0) {
                float sc0 = 2.f + 2.f * p0 + ubs0;
                float sc1 = 2.f + 2.f * p1 + ubs1;
                int tgt = dir[e];
                float mm = fmaxf(sc0, sc1);
                float lse = mm + logf(expf(sc0 - mm) + expf(sc1 - mm));
                lloss += lse - ((tgt == 0) ? sc0 : sc1);
                int am = (sc1 > sc0) ? 1 : 0;
                lhit += (am == tgt) ? 1.f : 0.f;
            }
        }
        if (l == 0) { red2[w][0] = lloss; red2[w][1] = lhit; }
        __syncthreads();
        if (threadIdx.x == 0) {
            float* pr = part + (size_t)(256 + blockIdx.x) * 8;
            pr[0] = 0.f; pr[1] = 0.f; pr[2] = 0.f;
            pr[3] = red2[0][0] + red2[1][0] + red2[2][0] + red2[3][0];
            pr[4] = red2[0][1] + red2[1][1] + red2[2][1] + red2[3][1];
        }
    } else {
        int b = blockIdx.x - 256, j = threadIdx.x;
        float* pr = part + (size_t)(512 + b) * 8;

        const int*   ip = roi + b * K_;
        const float* wp = row_w + b * K_;
        float ave = 0.f, wsum = 0.f;
        #pragma unroll
        for (int k = 0; k < K_; k++) {
            int id = ip[k]; float w = wp[k];
            ave += w * hbuf[(size_t)id * H_ + j];
            wsum += w;
        }
        ave /= fmaxf(wsum, 1e-8f);
        float inner = blk_sum((j == 0) ? -ave * ave : ave * ave, red);
        float ro = ave / sqrtf(fmaxf(-inner, 1e-8f));

        int   rw = rwid[b];
        float er = emb[(size_t)rw * H_ + j];
        float ctxj = (j < L_) ? xtv[(size_t)b * L_ + j] : 0.f;
        if (j == 0) { shs[0] = er; shs[1] = ro; shs[2] = ctxj; }
        if (j < L_) ctxs[j] = ctxj;
        __syncthreads();
        float t1sq = fmaxf(shs[0] * shs[0] + shs[1] * shs[1] - 1.f, 1e-8f);
        float sh0  = sqrtf(fmaxf(t1sq + shs[2] * shs[2] - 1.f, 1e-8f));

        float p0, p1;
        if (j >= 1) {
            p0 = er * ucls[j] + ro * ucls[255 + j];
            p1 = er * ucls[UD + j] + ro * ucls[UD + 255 + j];
            if (j < L_) { p0 += ctxj * ucls[510 + j]; p1 += ctxj * ucls[UD + 510 + j]; }
        } else {
            p0 = -sh0 * ucls[0];
            p1 = -sh0 * ucls[UD];
        }
        float s0 = 2.f + 2.f * blk_sum(p0, red) + ubias[0];
        float s1 = 2.f + 2.f * blk_sum(p1, red) + ubias[1];
        if (j == 0) {
            float mm = fmaxf(s0, s1);
            float lse = mm + logf(expf(s0 - mm) + expf(s1 - mm));
            int am = (s1 > s0) ? 1 : 0;
            pr[3] = lse - s0;
            pr[4] = (am == 0) ? 1.f : 0.f;
        }

        float c0 = shs[2];
        float z0 = sqrtf(fmaxf(c0 * c0, 1e-8f));
        __syncthreads();
        for (int v = j; v < V_; v += 256) {
            const float* wv = wcls + (size_t)v * ZD;
            float d = -z0 * wv[0];
            for (int i = 1; i < L_; i++) d += ctxs[i] * wv[255 + i];
            sc[v] = 2.f + 2.f * d + wbias[v];
        }
        __syncthreads();
        float mx = -1e30f; int mi = 0;
        for (int v = j; v < V_; v += 256) { float x = sc[v]; if (x > mx) { mx = x; mi = v; } }
        red[j] = mx; redi[j] = mi;
        __syncthreads();
        for (int o = 128; o > 0; o >>= 1) {
            if (j < o) {
                float xo = red[j + o]; int io = redi[j + o];
                if (xo > red[j] || (xo == red[j] && io < redi[j])) { red[j] = xo; redi[j] = io; }
            }
            __syncthreads();
        }
        float gm = red[0]; int ga = redi[0];
        __syncthreads();
        float se = 0.f;
        for (int v = j; v < V_; v += 256) se += expf(sc[v] - gm);
        red[j] = se;
        __syncthreads();
        for (int o = 128; o > 0; o >>= 1) { if (j < o) red[j] += red[j + o]; __syncthreads(); }
        if (j == 0) {
            float lse = gm + logf(red[0]);
            pr[0] = lse - sc[rw];
            pr[1] = (ga == rw) ? 1.f : 0.f;
            pr[2] = 0.f;
        }
    }

    // ---- last-block completion: fold finalize in (saves a launch) ----
    __syncthreads();
    if (threadIdx.x == 0) {
        __threadfence();   // drain this block's partial writes to device scope
        int done = __hip_atomic_fetch_add(counter, 1, __ATOMIC_ACQ_REL,
                                          __HIP_MEMORY_SCOPE_AGENT);
        lastf = (done == 511) ? 1 : 0;
    }
    __syncthreads();
    if (lastf) {
        int j = threadIdx.x;
        #pragma unroll
        for (int c = 0; c < 5; c++)
            fred[j][c] = llc_loadf(part + (size_t)j * 8 + c)
                       + llc_loadf(part + (size_t)(j + 256) * 8 + c)
                       + llc_loadf(part + (size_t)(j + 512) * 8 + c);
        __syncthreads();
        for (int o = 128; o > 0; o >>= 1) {
            if (j < o) {
                #pragma unroll
                for (int c = 0; c < 5; c++) fred[j][c] += fred[j + o][c];
            }
            __syncthreads();
        }
        if (j == 0) {
            out[0] = fred[0][0] / (float)B_;
            out[1] = fred[0][3] / (float)B_;
            out[2] = fred[0][1] / ((float)B_ + fred[0][2]);
            out[3] = fred[0][4] / (float)(E_ + B_);
        }
    }
}

// ---------------- launch ----------------

extern "C" void kernel_launch(void* const* d_in, const int* in_sizes, int n_in,
                              void* d_out, int out_size, void* d_ws, size_t ws_size,
                              hipStream_t stream) {
    const int*   wid   = (const int*)d_in[0];
    const int*   nhi   = (const int*)d_in[1];
    const float* nhw   = (const float*)d_in[2];
    const int*   noi   = (const int*)d_in[3];
    const float* now_w = (const float*)d_in[4];
    const int*   bidx  = (const int*)d_in[5];
    const int*   dir   = (const int*)d_in[6];
    const int*   pt    = (const int*)d_in[7];
    const int*   rwid  = (const int*)d_in[8];
    const int*   roi   = (const int*)d_in[9];
    const float* row_w = (const float*)d_in[10];
    const float* xtv   = (const float*)d_in[11];
    const float* emb   = (const float*)d_in[12];
    const float* W0    = (const float*)d_in[13];
    const float* b0    = (const float*)d_in[14];
    const float* s0    = (const float*)d_in[15];
    const float* W1    = (const float*)d_in[16];
    const float* b1    = (const float*)d_in[17];
    const float* s1    = (const float*)d_in[18];
    const float* wcls  = (const float*)d_in[19];
    const float* wbias = (const float*)d_in[20];
    const float* ucls  = (const float*)d_in[21];
    const float* ubias = (const float*)d_in[22];

    float* ws    = (float*)d_ws;
    float* hbuf  = ws;                                          // (E+1)*256 f32
    u64*   hbuf2 = (u64*)(hbuf + (size_t)(E_ + 1) * H_);        // (E+1)*128 u64 tagged pairs
    u64*   hbuf3 = hbuf2 + (size_t)(E_ + 1) * 128;              // E_ u64 tagged f32 h0
    float* part  = (float*)(hbuf3 + E_);                        // 768*8 f32
    int*   counter = (int*)(part + 768 * 8);                    // 256 ints (word 0 used)
    float* basew = (float*)(counter + 256);                     // 780*256 f32
    _Float16* W0P  = (_Float16*)(basew + (size_t)V_ * H_);      // 65536 fp16
    _Float16* W1HP = W0P + 65536;                               // 65536 fp16
    _Float16* Wh   = W1HP + 65536;                              // VP*KP fp16
    float* out  = (float*)d_out;

    prep_k<<<(S_TOTAL + 255) / 256, 256, 0, stream>>>(W0, W1, wcls, emb, b1,
                                                      hbuf, hbuf2, hbuf3, counter,
                                                      W0P, W1HP, Wh, basew);

    scan_flow<<<M_, 256, 0, stream>>>(hbuf, hbuf2, hbuf3, W0P, b0, s0, W1HP, s1,
                                      emb, wid, nhi, nhw, basew,
                                      Wh, wbias, pt, dir, bidx, xtv, part);

    stoproot_k<<<512, 256, 0, stream>>>(hbuf, emb, xtv, wid, noi, now_w, bidx, dir,
                                        rwid, roi, row_w, wcls, wbias, ucls, ubias,
                                        part, counter, out);
}

// Round 11
// 572.769 us; speedup vs baseline: 1.0709x; 1.0709x over previous
//
#include <hip/hip_runtime.h>
#include <math.h>

// R11 = exact restore of the R6 configuration (best measured: 575.4 us).
// R7-R10 fusion experiments all regressed (+28..38 us); mega stable ~425 us.
// Structure: prep -> basew -> scan_flow(+fused gemm/CE tail) -> stoproot -> finalize.

#define T_ 64
#define M_ 256
#define K_ 6
#define B_ 256
#define H_ 256
#define L_ 128
#define V_ 780
#define E_ (T_*M_)       // 16384
#define ZD 383           // H+L-1
#define UD 638           // 2H+L-2
#define KP 384           // ZD padded for MFMA
#define VP 832           // V padded to 13*64
#define TAG_PAD 0x7fffffffu

typedef __attribute__((ext_vector_type(8))) _Float16 half8v;
typedef __attribute__((ext_vector_type(2))) _Float16 half2v;
typedef __attribute__((ext_vector_type(4))) float f32x4v;
typedef unsigned long long u64;

// ---------------- helpers ----------------

__device__ __forceinline__ float blk_sum(float v, float* red) {
    int j = threadIdx.x;
    #pragma unroll
    for (int o = 32; o > 0; o >>= 1) v += __shfl_down(v, o, 64);
    __syncthreads();
    if ((j & 63) == 0) red[j >> 6] = v;
    __syncthreads();
    return red[0] + red[1] + red[2] + red[3];
}

__device__ __forceinline__ float wave_sum(float v) {
    #pragma unroll
    for (int o = 32; o > 0; o >>= 1) v += __shfl_xor(v, o, 64);
    return v;
}

__device__ __forceinline__ _Float16 f2h(float x) { return (_Float16)x; }

// LLC-coherent (agent-scope) accessors for cross-block state
__device__ __forceinline__ u64 llc_load8(const u64* p) {
    return __hip_atomic_load(p, __ATOMIC_RELAXED, __HIP_MEMORY_SCOPE_AGENT);
}
__device__ __forceinline__ void llc_store8(u64* p, u64 v) {
    __hip_atomic_store(p, v, __ATOMIC_RELAXED, __HIP_MEMORY_SCOPE_AGENT);
}

// ---------------- fused prep ----------------
// hbuf: only PAD row E needs init (scan fully overwrites rows 0..E-1).
// hbuf2: (E+1)x128 tagged pairs {2 x fp16, tag}; init tag 0; PAD row
// pre-tagged TAG_PAD with (1,0,...,0). hbuf3: per-row tagged f32 h0.

#define PREP_R0 H_                       // hbuf PAD row
#define PREP_RT ((E_ + 1) * 128)         // hbuf2
#define PREP_RH3 E_                      // hbuf3
#define PREP_R1 65536                    // W0P  (16*8*64*8)
#define PREP_R2 65536                    // W1HP (16*8*64*8)
#define PREP_R3 (VP * KP)                // Wh
#define PREP_R4 65536                    // W1T (f32, 256x256)
#define PREP_TOTAL (PREP_R0 + PREP_RT + PREP_RH3 + PREP_R1 + PREP_R2 + PREP_R3 + PREP_R4)

__global__ __launch_bounds__(256) void prep_k(const float* __restrict__ W0,
                                              const float* __restrict__ W1,
                                              const float* __restrict__ wcls,
                                              float* __restrict__ hbuf,
                                              u64* __restrict__ hbuf2,
                                              u64* __restrict__ hbuf3,
                                              _Float16* __restrict__ W0P,
                                              _Float16* __restrict__ W1HP,
                                              _Float16* __restrict__ Wh,
                                              float* __restrict__ W1T) {
    int idx = blockIdx.x * 256 + threadIdx.x;
    if (idx < PREP_R0) {
        hbuf[(size_t)E_ * H_ + idx] = (idx == 0) ? 1.f : 0.f;
        return;
    }
    idx -= PREP_R0;
    if (idx < PREP_RT) {
        int row = idx >> 7, cp = idx & 127;
        u64 val = 0ull;
        if (row == E_) {
            unsigned int lo = (cp == 0) ? 0x3C00u : 0u;   // fp16 1.0 in col 0
            val = ((u64)TAG_PAD << 32) | lo;
        }
        hbuf2[idx] = val;
        return;
    }
    idx -= PREP_RT;
    if (idx < PREP_RH3) {
        hbuf3[idx] = 0ull;
        return;
    }
    idx -= PREP_RH3;
    if (idx < PREP_R1) {
        // W0P[((nt*8+ks)*64+l)*8+e] = W0[(nt*16+(l&15)) * H + ks*32+(l>>4)*8+e]
        int e = idx & 7, l = (idx >> 3) & 63, ks = (idx >> 9) & 7, nt = idx >> 12;
        int jj = nt * 16 + (l & 15);
        int ii = ks * 32 + (l >> 4) * 8 + e;
        W0P[idx] = f2h(W0[(size_t)jj * H_ + ii]);
        return;
    }
    idx -= PREP_R1;
    if (idx < PREP_R2) {
        // same packing, but column map ii -> {0, 256..510} of W1
        int e = idx & 7, l = (idx >> 3) & 63, ks = (idx >> 9) & 7, nt = idx >> 12;
        int jj = nt * 16 + (l & 15);
        int ii = ks * 32 + (l >> 4) * 8 + e;
        float v = (ii == 0) ? W1[(size_t)jj * (2 * H_ - 1)]
                            : W1[(size_t)jj * (2 * H_ - 1) + 255 + ii];
        W1HP[idx] = f2h(v);
        return;
    }
    idx -= PREP_R2;
    if (idx < PREP_R3) {
        int v = idx / KP, k = idx - v * KP;
        float val = (v < V_ && k < ZD) ? wcls[(size_t)v * ZD + k] : 0.f;
        Wh[idx] = f2h(val);
        return;
    }
    idx -= PREP_R3;
    if (idx < PREP_R4) {
        int i = idx >> 8, j = idx & 255;
        W1T[idx] = (i >= 1) ? W1[(size_t)j * (2 * H_ - 1) + i] : 0.f;
    }
}

// ---------------- base_w: static (per word-id) half of the W1 GEMV ----------------

__global__ __launch_bounds__(256) void basew_k(const float* __restrict__ emb,
                                               const float* __restrict__ W1T,
                                               const float* __restrict__ b1,
                                               float* __restrict__ basew) {
    int v = blockIdx.x, j = threadIdx.x;
    __shared__ float cxs[256];
    cxs[j] = emb[(size_t)v * H_ + j];
    __syncthreads();
    float acc = b1[j];
    #pragma unroll 8
    for (int i = 1; i < 256; i++) acc = fmaf(cxs[i], W1T[i * 256 + j], acc);
    basew[(size_t)v * H_ + j] = acc;
}

// ---------------- dataflow scan + FUSED msg GEMM/CE tail ----------------
// Batch-poll validate, cross-step prefetch, per-wave zz strips, 3 barriers/step;
// publish = tagged fp16 pairs + tagged f32 h0 + plain f32 row (stoproot reads
// the plain row across the kernel boundary with cheap cached loads).

__global__ __launch_bounds__(256, 1) void scan_flow(float* __restrict__ hbuf,
        u64* __restrict__ hbuf2, u64* __restrict__ hbuf3,
        const _Float16* __restrict__ W0P, const float* __restrict__ b0, const float* __restrict__ s0p,
        const _Float16* __restrict__ W1HP, const float* __restrict__ s1p,
        const float* __restrict__ emb, const int* __restrict__ wid,
        const int* __restrict__ nhi, const float* __restrict__ nhw,
        const float* __restrict__ basew,
        const _Float16* __restrict__ Wh, const float* __restrict__ wbias,
        const int* __restrict__ pt, const int* __restrict__ dir,
        const int* __restrict__ bidx, const float* __restrict__ xtv,
        float* __restrict__ part) {
    int tid = threadIdx.x;
    int w = tid >> 6, l = tid & 63;
    int quad = l >> 4, col = l & 15;
    int m = blockIdx.x;
    int j0 = 4 * l;
    int cp = tid & 127;            // this thread's colpair (cols 2cp, 2cp+1)
    int rsel = tid >> 7;           // 0 or 1: rows {rsel, rsel+2, rsel+4}

    __shared__ __align__(16) _Float16 hn16[16][264];   // rows 0..5 staged
    __shared__ __align__(16) _Float16 zzs[4][264];     // per-wave zh strips
    __shared__ __align__(16) float Ys[6][256];
    __shared__ __align__(16) float y2s[256];
    // gemm-tail buffers
    __shared__ __align__(16) _Float16 As[64][392];
    __shared__ __align__(16) _Float16 Bsf[64][392];
    __shared__ __align__(16) float SCs[64][68];
    __shared__ float rmax[64], rsum[64], rval[64];
    __shared__ int   rargi[64];

    // ---- one-time: wave w's weight slices (nt = 4w..4w+3) into registers ----
    half8v w0f[4][8], w1f[4][8];
    #pragma unroll
    for (int q = 0; q < 4; q++) {
        int nt = 4 * w + q;
        #pragma unroll
        for (int ks = 0; ks < 8; ks++) {
            w0f[q][ks] = *(const half8v*)(W0P + ((size_t)(nt * 8 + ks) * 64 + l) * 8);
            w1f[q][ks] = *(const half8v*)(W1HP + ((size_t)(nt * 8 + ks) * 64 + l) * 8);
        }
    }

    float es0 = expf(s0p[0]);
    float es1 = expf(s1p[0]);
    float4 bj4 = *(const float4*)(b0 + j0);

    // ---- prologue: issue step-0 pair loads (3 per thread) ----
    unsigned int tagx[3];
    const u64* pp[3];
    u64 pvv[3];
    #pragma unroll
    for (int p = 0; p < 3; p++) {
        int row = 2 * p + rsel;
        int id = nhi[(size_t)m * K_ + row];              // e = 0*M_+m
        tagx[p] = (id < E_) ? (unsigned int)(id >> 8) + 1u : TAG_PAD;
        pp[p] = hbuf2 + ((size_t)id << 7) + cp;
        pvv[p] = llc_load8(pp[p]);
    }

    for (int t = 0; t < T_; t++) {
        int e = t * M_ + m;
        const float* wp = nhw + e * K_;

        // per-step scalars (cached loads; latency hides under validate/W0)
        float wk[K_];
        #pragma unroll
        for (int k = 0; k < K_; k++) wk[k] = wp[k];
        int wde = wid[e];
        float4 bw4 = *(const float4*)(basew + (size_t)wde * H_ + j0);
        float cx0 = emb[(size_t)wde * H_];

        // ---- batch-poll validate: one parallel RT per retry round ----
        for (;;) {
            bool ok = ((unsigned int)(pvv[0] >> 32) == tagx[0])
                   && ((unsigned int)(pvv[1] >> 32) == tagx[1])
                   && ((unsigned int)(pvv[2] >> 32) == tagx[2]);
            if (ok) break;
            __builtin_amdgcn_s_sleep(1);
            #pragma unroll
            for (int p = 0; p < 3; p++)
                if ((unsigned int)(pvv[p] >> 32) != tagx[p]) pvv[p] = llc_load8(pp[p]);
        }
        #pragma unroll
        for (int p = 0; p < 3; p++)
            *(unsigned int*)&hn16[2 * p + rsel][cp * 2] = (unsigned int)pvv[p];
        __syncthreads();                                           // S1: rows staged

        // ---- prefetch step t+1's pairs (fly under W0/phaseA/W1/final) ----
        if (t + 1 < T_) {
            #pragma unroll
            for (int p = 0; p < 3; p++) {
                int row = 2 * p + rsel;
                int id = nhi[(size_t)(e + M_) * K_ + row];
                tagx[p] = (id < E_) ? (unsigned int)(id >> 8) + 1u : TAG_PAD;
                pp[p] = hbuf2 + ((size_t)id << 7) + cp;
                pvv[p] = llc_load8(pp[p]);
            }
        }

        // ---- W0 GEMM via MFMA: A from LDS, B from registers ----
        f32x4v acc[4];
        #pragma unroll
        for (int q = 0; q < 4; q++) acc[q] = (f32x4v){0.f, 0.f, 0.f, 0.f};
        #pragma unroll
        for (int ks = 0; ks < 8; ks++) {
            half8v afr = *(const half8v*)&hn16[col][ks * 32 + quad * 8];
            #pragma unroll
            for (int q = 0; q < 4; q++)
                acc[q] = __builtin_amdgcn_mfma_f32_16x16x32_f16(afr, w0f[q][ks], acc[q], 0, 0, 0);
        }
        #pragma unroll
        for (int q = 0; q < 4; q++) {
            int nt = 4 * w + q;
            #pragma unroll
            for (int rr = 0; rr < 4; rr++) {
                int row = quad * 4 + rr;
                if (row < 6) Ys[row][nt * 16 + col] = acc[q][rr];
            }
        }
        __syncthreads();                                           // S2: Ys ready

        // ---- nonlinear phase A (wave-redundant): interleaved butterflies ----
        float y[K_][4];
        #pragma unroll
        for (int k = 0; k < K_; k++) {
            float4 yv = *(const float4*)&Ys[k][j0];
            y[k][0] = yv.x + bj4.x; y[k][1] = yv.y + bj4.y;
            y[k][2] = yv.z + bj4.z; y[k][3] = yv.w + bj4.w;
        }
        float c[K_];
        #pragma unroll
        for (int k = 0; k < K_; k++) {
            float cc = y[k][0] * y[k][0] + y[k][1] * y[k][1]
                     + y[k][2] * y[k][2] + y[k][3] * y[k][3];
            if (l == 0) cc -= y[k][0] * y[k][0];         // exclude j==0 term
            c[k] = cc;
        }
        #pragma unroll
        for (int o = 32; o > 0; o >>= 1) {
            #pragma unroll
            for (int k = 0; k < K_; k++) c[k] += __shfl_xor(c[k], o, 64);
        }
        float y0b[K_];
        #pragma unroll
        for (int k = 0; k < K_; k++) y0b[k] = __shfl(y[k][0], 0, 64);

        float ave[4] = {0.f, 0.f, 0.f, 0.f};
        float wsum = 0.f;
        #pragma unroll
        for (int k = 0; k < K_; k++) {
            float tm = es0 / (1.f + expf(-y0b[k])) + 1.1f;
            float scv = sqrtf((tm * tm - 1.f) / fmaxf(c[k], 1e-8f));
            #pragma unroll
            for (int c2 = 0; c2 < 4; c2++) {
                float h1v = (l == 0 && c2 == 0) ? tm : y[k][c2] * scv;
                ave[c2] += wk[k] * h1v;
            }
            wsum += wk[k];
        }
        float inv = 1.f / fmaxf(wsum, 1e-8f);
        float innl = 0.f;
        #pragma unroll
        for (int c2 = 0; c2 < 4; c2++) { ave[c2] *= inv; innl += ave[c2] * ave[c2]; }
        if (l == 0) innl -= 2.f * ave[0] * ave[0];       // j==0 contributes -ave0^2
        float inner = wave_sum(innl);
        float rsc = 1.f / sqrtf(fmaxf(-inner, 1e-8f));

        // each wave writes ITS OWN zz strip (no cross-wave barrier needed)
        #pragma unroll
        for (int c2 = 0; c2 < 4; c2++) {
            int j = j0 + c2;
            float h1m = ave[c2] * rsc;
            if (j == 0) {
                zzs[w][0] = f2h(sqrtf(fmaxf(cx0 * cx0 + h1m * h1m - 1.f, 1e-8f)));
            } else {
                zzs[w][j] = f2h(h1m);
            }
        }

        // ---- W1H GEMV via MFMA (K=256): A from own zz strip, B from registers ----
        f32x4v a2[4];
        #pragma unroll
        for (int q = 0; q < 4; q++) a2[q] = (f32x4v){0.f, 0.f, 0.f, 0.f};
        #pragma unroll
        for (int ks = 0; ks < 8; ks++) {
            half8v zfr = *(const half8v*)&zzs[w][ks * 32 + quad * 8];
            #pragma unroll
            for (int q = 0; q < 4; q++)
                a2[q] = __builtin_amdgcn_mfma_f32_16x16x32_f16(zfr, w1f[q][ks], a2[q], 0, 0, 0);
        }
        if (quad == 0) {
            #pragma unroll
            for (int q = 0; q < 4; q++) y2s[(4 * w + q) * 16 + col] = a2[q][0];
        }
        __syncthreads();                                           // S4: y2 ready

        // ---- final nonlinear + publish row (wave 0; tagged pairs first) ----
        if (w == 0) {
            float4 y2v = *(const float4*)&y2s[j0];
            float y2[4] = {y2v.x + bw4.x, y2v.y + bw4.y, y2v.z + bw4.z, y2v.w + bw4.w};
            float c2s = y2[0] * y2[0] + y2[1] * y2[1] + y2[2] * y2[2] + y2[3] * y2[3];
            if (l == 0) c2s -= y2[0] * y2[0];
            float ssq2 = wave_sum(c2s);
            float y20 = __shfl(y2[0], 0, 64);
            float tm2 = es1 / (1.f + expf(-y20)) + 1.1f;
            float sc2 = sqrtf((tm2 * tm2 - 1.f) / fmaxf(ssq2, 1e-8f));
            float hv0 = (l == 0) ? tm2 : y2[0] * sc2;
            float hv1 = y2[1] * sc2, hv2 = y2[2] * sc2, hv3 = y2[3] * sc2;

            // tagged fp16 pairs FIRST (what scan consumers wait on)
            unsigned int tag = (unsigned int)t + 1u;
            union { half2v h; unsigned int u; } c01, c23;
            c01.h.x = f2h(hv0); c01.h.y = f2h(hv1);
            c23.h.x = f2h(hv2); c23.h.y = f2h(hv3);
            u64* pb = hbuf2 + ((size_t)e << 7) + 2 * l;
            llc_store8(pb,     ((u64)tag << 32) | c01.u);
            llc_store8(pb + 1, ((u64)tag << 32) | c23.u);

            // tagged exact f32 h0 for the fused gemm tail (lane 0)
            if (l == 0) {
                union { float f; unsigned int u; } h0b; h0b.f = tm2;
                llc_store8(hbuf3 + e, ((u64)tag << 32) | h0b.u);
            }

            // plain f32 row for stoproot (kernel-boundary visible, cached reads)
            float4 out4 = {hv0, hv1, hv2, hv3};
            *(float4*)(hbuf + (size_t)e * H_ + j0) = out4;
        }
        // no trailing barrier: S1(t+1) orders next-step hn16 writes after S4(t)
    }

    // ================= fused msg GEMM + CE tail =================
    {
        int m0 = m * 64;   // this block's 64 e-rows

        // ---- stage As cols 0..255 from hbuf2 tagged pairs (32/thread, batch-poll) ----
        u64 gpv[32];
        #pragma unroll
        for (int i = 0; i < 32; i++) {
            int p = tid + i * 256;
            int row = p >> 7, cpp = p & 127;
            gpv[i] = llc_load8(hbuf2 + ((size_t)(m0 + row) << 7) + cpp);
        }
        for (;;) {
            bool ok = true;
            #pragma unroll
            for (int i = 0; i < 32; i++) {
                int row = (tid + i * 256) >> 7;
                unsigned int tg = (unsigned int)((m0 + row) >> 8) + 1u;
                if ((unsigned int)(gpv[i] >> 32) != tg) ok = false;
            }
            if (ok) break;
            __builtin_amdgcn_s_sleep(1);
            #pragma unroll
            for (int i = 0; i < 32; i++) {
                int p = tid + i * 256;
                int row = p >> 7, cpp = p & 127;
                unsigned int tg = (unsigned int)((m0 + row) >> 8) + 1u;
                if ((unsigned int)(gpv[i] >> 32) != tg)
                    gpv[i] = llc_load8(hbuf2 + ((size_t)(m0 + row) << 7) + cpp);
            }
        }
        #pragma unroll
        for (int i = 0; i < 32; i++) {
            int p = tid + i * 256;
            int row = p >> 7, cpp = p & 127;
            *(unsigned int*)&As[row][2 * cpp] = (unsigned int)gpv[i];
        }
        // ---- ctx cols 256..383 from xtv ----
        #pragma unroll
        for (int i = 0; i < 16; i++) {
            int p = tid + i * 256;
            int row = p >> 6, k2 = (p & 63) * 2;
            int bi = bidx[m0 + row];
            int ca = 256 + k2;
            half2v hv;
            hv.x = (ca <= 382) ? f2h(xtv[(size_t)bi * L_ + (ca - 255)]) : (_Float16)0.f;
            hv.y = (ca + 1 <= 382) ? f2h(xtv[(size_t)bi * L_ + (ca - 254)]) : (_Float16)0.f;
            *(half2v*)&As[row][ca] = hv;
        }
        // ---- col 0: -z0 from exact f32 h0 (hbuf3, self-validating) ----
        if (tid < 64) {
            int e2 = m0 + tid;
            unsigned int tg = (unsigned int)(e2 >> 8) + 1u;
            u64 hv3 = llc_load8(hbuf3 + e2);
            while ((unsigned int)(hv3 >> 32) != tg) {
                __builtin_amdgcn_s_sleep(1);
                hv3 = llc_load8(hbuf3 + e2);
            }
            union { unsigned int u; float f; } h0c; h0c.u = (unsigned int)hv3;
            int bi = bidx[e2];
            float c0 = xtv[(size_t)bi * L_];
            float z0 = sqrtf(fmaxf(h0c.f * h0c.f + c0 * c0 - 1.f, 1e-8f));
            As[tid][0] = f2h(-z0);
            rmax[tid] = -1e30f; rsum[tid] = 0.f; rargi[tid] = 0; rval[tid] = 0.f;
        }
        __syncthreads();

        int q8 = quad * 8;
        for (int nt = 0; nt < 13; nt++) {
            int n0 = nt * 64;
            #pragma unroll
            for (int i = 0; i < 12; i++) {
                int uu = tid + i * 256;
                int row = uu / 48, c8 = (uu % 48) * 8;
                *(uint4*)&Bsf[row][c8] = *(const uint4*)(Wh + (size_t)(n0 + row) * KP + c8);
            }
            __syncthreads();

            f32x4v gacc[4];
            #pragma unroll
            for (int mt = 0; mt < 4; mt++) gacc[mt] = (f32x4v){0.f, 0.f, 0.f, 0.f};
            #pragma unroll
            for (int ks = 0; ks < 12; ks++) {
                half8v bfr = *(const half8v*)&Bsf[w * 16 + col][ks * 32 + q8];
                #pragma unroll
                for (int mt = 0; mt < 4; mt++) {
                    half8v afr = *(const half8v*)&As[mt * 16 + col][ks * 32 + q8];
                    gacc[mt] = __builtin_amdgcn_mfma_f32_16x16x32_f16(afr, bfr, gacc[mt], 0, 0, 0);
                }
            }
            int ncol = n0 + w * 16 + col;
            float bias = (ncol < V_) ? wbias[ncol] : 0.f;
            #pragma unroll
            for (int mt = 0; mt < 4; mt++) {
                #pragma unroll
                for (int rr = 0; rr < 4; rr++)
                    SCs[mt * 16 + quad * 4 + rr][w * 16 + col] = 2.f + 2.f * gacc[mt][rr] + bias;
            }
            __syncthreads();

            {
                int row = tid >> 2, prt = tid & 3;
                int tg = pt[m0 + row];
                float vals[16];
                float lm = -1e30f; int li = 0;
                #pragma unroll
                for (int cc = 0; cc < 16; cc++) {
                    int nc = n0 + prt * 16 + cc;
                    float x = (nc < V_) ? SCs[row][prt * 16 + cc] : -1e30f;
                    vals[cc] = x;
                    if (x > lm) { lm = x; li = nc; }
                    if (nc == tg) rval[row] = x;
                }
                #pragma unroll
                for (int o = 1; o < 4; o <<= 1) {
                    float om = __shfl_xor(lm, o, 64);
                    int   oi = __shfl_xor(li, o, 64);
                    if (om > lm || (om == lm && oi < li)) { lm = om; li = oi; }
                }
                float ls = 0.f;
                #pragma unroll
                for (int cc = 0; cc < 16; cc++) {
                    int nc = n0 + prt * 16 + cc;
                    if (nc < V_) ls += expf(vals[cc] - lm);
                }
                #pragma unroll
                for (int o = 1; o < 4; o <<= 1) ls += __shfl_xor(ls, o, 64);
                if (prt == 0) {
                    float om = rmax[row], os = rsum[row];
                    float nm = fmaxf(om, lm);
                    rsum[row] = os * expf(om - nm) + ls * expf(lm - nm);
                    if (lm > om) rargi[row] = li;
                    rmax[row] = nm;
                }
            }
            __syncthreads();
        }

        if (tid < 64) {
            int e2 = m0 + tid;
            int tg = pt[e2];
            float pm = (float)dir[e2];
            float lse = rmax[tid] + logf(rsum[tid]);
            float lloss = pm * (lse - rval[tid]);
            float lhit  = pm * ((rargi[tid] == tg) ? 1.f : 0.f);
            float lpm   = pm;
            lloss = wave_sum(lloss);
            lhit  = wave_sum(lhit);
            lpm   = wave_sum(lpm);
            if (tid == 0) {
                float* pr = part + (size_t)m * 8;
                pr[0] = lloss; pr[1] = lhit; pr[2] = lpm;
                pr[3] = 0.f; pr[4] = 0.f;
            }
        }
    }
}

// ---------------- fused stop head (blocks 0..255) + root (blocks 256..511) ----------------

__global__ __launch_bounds__(256) void stoproot_k(const float* __restrict__ hbuf,
        const float* __restrict__ emb, const float* __restrict__ xtv,
        const int* __restrict__ wid, const int* __restrict__ noi, const float* __restrict__ now_w,
        const int* __restrict__ bidx, const int* __restrict__ dir,
        const int* __restrict__ rwid, const int* __restrict__ roi, const float* __restrict__ row_w,
        const float* __restrict__ wcls, const float* __restrict__ wbias,
        const float* __restrict__ ucls, const float* __restrict__ ubias,
        float* __restrict__ part) {
    __shared__ float red[256];
    __shared__ int   redi[256];
    __shared__ float shs[4];
    __shared__ float ctxs[L_];
    __shared__ float sc[V_];
    __shared__ float red2[4][2];

    if (blockIdx.x < 256) {
        int w = threadIdx.x >> 6, l = threadIdx.x & 63;
        int wg = blockIdx.x * 4 + w;

        float ua0[4], ub0[4], ua1[4], ub1[4], uc0[2], uc1[2];
        #pragma unroll
        for (int s = 0; s < 4; s++) {
            int j = s * 64 + l;
            ua0[s] = ucls[j];        ub0[s] = ucls[255 + j];
            ua1[s] = ucls[UD + j];   ub1[s] = ucls[UD + 255 + j];
        }
        #pragma unroll
        for (int s = 0; s < 2; s++) {
            int j = s * 64 + l;
            uc0[s] = ucls[510 + j];  uc1[s] = ucls[UD + 510 + j];
        }
        float u00 = ucls[0], u10 = ucls[UD];
        float ubs0 = ubias[0], ubs1 = ubias[1];

        float lloss = 0.f, lhit = 0.f;
        for (int i = 0; i < 16; i++) {
            int e = wg * 16 + i;
            const int*   ip = noi + e * K_;
            const float* wp = now_w + e * K_;
            float ave[4] = {0.f, 0.f, 0.f, 0.f};
            float wsum = 0.f;
            #pragma unroll
            for (int k = 0; k < K_; k++) {
                int id = ip[k]; float wt = wp[k];
                wsum += wt;
                const float* hr = hbuf + (size_t)id * H_;
                #pragma unroll
                for (int s = 0; s < 4; s++) ave[s] += wt * hr[s * 64 + l];
            }
            float inv = 1.f / fmaxf(wsum, 1e-8f);
            float innl = 0.f;
            #pragma unroll
            for (int s = 0; s < 4; s++) { ave[s] *= inv; innl += ave[s] * ave[s]; }
            if (l == 0) innl -= 2.f * ave[0] * ave[0];
            float inner = wave_sum(innl);
            float cs = 1.f / sqrtf(fmaxf(-inner, 1e-8f));

            int we = wid[e], bi = bidx[e];
            const float* er = emb + (size_t)we * H_;
            const float* cr = xtv + (size_t)bi * L_;

            float p0 = 0.f, p1 = 0.f;
            #pragma unroll
            for (int s = 0; s < 4; s++) {
                float cx = er[s * 64 + l];
                float co = ave[s] * cs;
                if (s == 0 && l == 0) {
                    float ctx0 = cr[0];
                    float t1sq = fmaxf(cx * cx + co * co - 1.f, 1e-8f);
                    float sh0 = sqrtf(fmaxf(t1sq + ctx0 * ctx0 - 1.f, 1e-8f));
                    p0 += -sh0 * u00; p1 += -sh0 * u10;
                } else {
                    p0 += cx * ua0[s] + co * ub0[s];
                    p1 += cx * ua1[s] + co * ub1[s];
                }
                if (s < 2) {
                    int j = s * 64 + l;
                    if (j >= 1) {
                        float ctx = cr[j];
                        p0 += ctx * uc0[s]; p1 += ctx * uc1[s];
                    }
                }
            }
            p0 = wave_sum(p0); p1 = wave_sum(p1);
            if (l == 0) {
                float sc0 = 2.f + 2.f * p0 + ubs0;
                float sc1 = 2.f + 2.f * p1 + ubs1;
                int tgt = dir[e];
                float mm = fmaxf(sc0, sc1);
                float lse = mm + logf(expf(sc0 - mm) + expf(sc1 - mm));
                lloss += lse - ((tgt == 0) ? sc0 : sc1);
                int am = (sc1 > sc0) ? 1 : 0;
                lhit += (am == tgt) ? 1.f : 0.f;
            }
        }
        if (l == 0) { red2[w][0] = lloss; red2[w][1] = lhit; }
        __syncthreads();
        if (threadIdx.x == 0) {
            float* pr = part + (size_t)(256 + blockIdx.x) * 8;
            pr[0] = 0.f; pr[1] = 0.f; pr[2] = 0.f;
            pr[3] = red2[0][0] + red2[1][0] + red2[2][0] + red2[3][0];
            pr[4] = red2[0][1] + red2[1][1] + red2[2][1] + red2[3][1];
        }
    } else {
        int b = blockIdx.x - 256, j = threadIdx.x;
        float* pr = part + (size_t)(512 + b) * 8;

        const int*   ip = roi + b * K_;
        const float* wp = row_w + b * K_;
        float ave = 0.f, wsum = 0.f;
        #pragma unroll
        for (int k = 0; k < K_; k++) {
            int id = ip[k]; float w = wp[k];
            ave += w * hbuf[(size_t)id * H_ + j];
            wsum += w;
        }
        ave /= fmaxf(wsum, 1e-8f);
        float inner = blk_sum((j == 0) ? -ave * ave : ave * ave, red);
        float ro = ave / sqrtf(fmaxf(-inner, 1e-8f));

        int   rw = rwid[b];
        float er = emb[(size_t)rw * H_ + j];
        float ctxj = (j < L_) ? xtv[(size_t)b * L_ + j] : 0.f;
        if (j == 0) { shs[0] = er; shs[1] = ro; shs[2] = ctxj; }
        if (j < L_) ctxs[j] = ctxj;
        __syncthreads();
        float t1sq = fmaxf(shs[0] * shs[0] + shs[1] * shs[1] - 1.f, 1e-8f);
        float sh0  = sqrtf(fmaxf(t1sq + shs[2] * shs[2] - 1.f, 1e-8f));

        float p0, p1;
        if (j >= 1) {
            p0 = er * ucls[j] + ro * ucls[255 + j];
            p1 = er * ucls[UD + j] + ro * ucls[UD + 255 + j];
            if (j < L_) { p0 += ctxj * ucls[510 + j]; p1 += ctxj * ucls[UD + 510 + j]; }
        } else {
            p0 = -sh0 * ucls[0];
            p1 = -sh0 * ucls[UD];
        }
        float s0 = 2.f + 2.f * blk_sum(p0, red) + ubias[0];
        float s1 = 2.f + 2.f * blk_sum(p1, red) + ubias[1];
        if (j == 0) {
            float mm = fmaxf(s0, s1);
            float lse = mm + logf(expf(s0 - mm) + expf(s1 - mm));
            int am = (s1 > s0) ? 1 : 0;
            pr[3] = lse - s0;
            pr[4] = (am == 0) ? 1.f : 0.f;
        }

        float c0 = shs[2];
        float z0 = sqrtf(fmaxf(c0 * c0, 1e-8f));
        __syncthreads();
        for (int v = j; v < V_; v += 256) {
            const float* wv = wcls + (size_t)v * ZD;
            float d = -z0 * wv[0];
            for (int i = 1; i < L_; i++) d += ctxs[i] * wv[255 + i];
            sc[v] = 2.f + 2.f * d + wbias[v];
        }
        __syncthreads();
        float mx = -1e30f; int mi = 0;
        for (int v = j; v < V_; v += 256) { float x = sc[v]; if (x > mx) { mx = x; mi = v; } }
        red[j] = mx; redi[j] = mi;
        __syncthreads();
        for (int o = 128; o > 0; o >>= 1) {
            if (j < o) {
                float xo = red[j + o]; int io = redi[j + o];
                if (xo > red[j] || (xo == red[j] && io < redi[j])) { red[j] = xo; redi[j] = io; }
            }
            __syncthreads();
        }
        float gm = red[0]; int ga = redi[0];
        __syncthreads();
        float se = 0.f;
        for (int v = j; v < V_; v += 256) se += expf(sc[v] - gm);
        red[j] = se;
        __syncthreads();
        for (int o = 128; o > 0; o >>= 1) { if (j < o) red[j] += red[j + o]; __syncthreads(); }
        if (j == 0) {
            float lse = gm + logf(red[0]);
            pr[0] = lse - sc[rw];
            pr[1] = (ga == rw) ? 1.f : 0.f;
            pr[2] = 0.f;
        }
    }
}

// ---------------- finalize ----------------

__global__ __launch_bounds__(256) void finalize2(const float* __restrict__ part,
                                                 float* __restrict__ out) {
    int j = threadIdx.x;
    __shared__ float red[256][5];
    #pragma unroll
    for (int c = 0; c < 5; c++)
        red[j][c] = part[(size_t)j * 8 + c] + part[(size_t)(j + 256) * 8 + c]
                  + part[(size_t)(j + 512) * 8 + c];
    __syncthreads();
    for (int o = 128; o > 0; o >>= 1) {
        if (j < o) {
            #pragma unroll
            for (int c = 0; c < 5; c++) red[j][c] += red[j + o][c];
        }
        __syncthreads();
    }
    if (j == 0) {
        out[0] = red[0][0] / (float)B_;
        out[1] = red[0][3] / (float)B_;
        out[2] = red[0][1] / ((float)B_ + red[0][2]);
        out[3] = red[0][4] / (float)(E_ + B_);
    }
}

// ---------------- launch ----------------

extern "C" void kernel_launch(void* const* d_in, const int* in_sizes, int n_in,
                              void* d_out, int out_size, void* d_ws, size_t ws_size,
                              hipStream_t stream) {
    const int*   wid   = (const int*)d_in[0];
    const int*   nhi   = (const int*)d_in[1];
    const float* nhw   = (const float*)d_in[2];
    const int*   noi   = (const int*)d_in[3];
    const float* now_w = (const float*)d_in[4];
    const int*   bidx  = (const int*)d_in[5];
    const int*   dir   = (const int*)d_in[6];
    const int*   pt    = (const int*)d_in[7];
    const int*   rwid  = (const int*)d_in[8];
    const int*   roi   = (const int*)d_in[9];
    const float* row_w = (const float*)d_in[10];
    const float* xtv   = (const float*)d_in[11];
    const float* emb   = (const float*)d_in[12];
    const float* W0    = (const float*)d_in[13];
    const float* b0    = (const float*)d_in[14];
    const float* s0    = (const float*)d_in[15];
    const float* W1    = (const float*)d_in[16];
    const float* b1    = (const float*)d_in[17];
    const float* s1    = (const float*)d_in[18];
    const float* wcls  = (const float*)d_in[19];
    const float* wbias = (const float*)d_in[20];
    const float* ucls  = (const float*)d_in[21];
    const float* ubias = (const float*)d_in[22];

    float* ws    = (float*)d_ws;
    float* hbuf  = ws;                                          // (E+1)*256 f32
    u64*   hbuf2 = (u64*)(hbuf + (size_t)(E_ + 1) * H_);        // (E+1)*128 u64 tagged pairs
    u64*   hbuf3 = hbuf2 + (size_t)(E_ + 1) * 128;              // E_ u64 tagged f32 h0
    float* part  = (float*)(hbuf3 + E_);                        // 768*8 f32
    float* basew = part + 768 * 8;                              // 780*256 f32
    float* W1T   = basew + (size_t)V_ * H_;                     // 65536 f32
    _Float16* W0P  = (_Float16*)(W1T + 65536);                  // 65536 fp16
    _Float16* W1HP = W0P + 65536;                               // 65536 fp16
    _Float16* Wh   = W1HP + 65536;                              // VP*KP fp16
    float* out  = (float*)d_out;

    prep_k<<<(PREP_TOTAL + 255) / 256, 256, 0, stream>>>(W0, W1, wcls, hbuf, hbuf2, hbuf3,
                                                         W0P, W1HP, Wh, W1T);
    basew_k<<<V_, 256, 0, stream>>>(emb, W1T, b1, basew);

    scan_flow<<<M_, 256, 0, stream>>>(hbuf, hbuf2, hbuf3, W0P, b0, s0, W1HP, s1,
                                      emb, wid, nhi, nhw, basew,
                                      Wh, wbias, pt, dir, bidx, xtv, part);

    stoproot_k<<<512, 256, 0, stream>>>(hbuf, emb, xtv, wid, noi, now_w, bidx, dir,
                                        rwid, roi, row_w, wcls, wbias, ucls, ubias, part);
    finalize2<<<1, 256, 0, stream>>>(part, out);
}